// Round 13
// baseline (119.060 us; speedup 1.0000x reference)
//
#include <hip/hip_runtime.h>

#define NT 64
#define NBMAX1 1024   // max buckets for the fast path (nodes <= 65536)
#define CAPB 2048     // payload slots per bucket (mean ~1279 here)
#define CHUNKMAX 8192 // max edges per fill block

typedef short bf16x8 __attribute__((ext_vector_type(8)));
typedef float f32x4  __attribute__((ext_vector_type(4)));

__device__ __forceinline__ unsigned short f2bf(float f) {
    unsigned u = __builtin_bit_cast(unsigned, f);
    unsigned r = (u + 0x7fffu + ((u >> 16) & 1u)) >> 16;   // round-nearest-even
    return (unsigned short)r;
}
__device__ __forceinline__ float bf2f(unsigned short h) {
    return __builtin_bit_cast(float, (unsigned)h << 16);
}
__device__ __forceinline__ unsigned pack2(float a, float b) {
    return (unsigned)f2bf(a) | ((unsigned)f2bf(b) << 16);
}

// ---------------------------------------------------------------------------
// Prep: W -> bf16 transposed [m][col][k], XOR-swizzled. Zero cursor[0..nb]
// (cursor[nb] = spill count; cursor[0..nb) rewritten by scanB).
// ---------------------------------------------------------------------------
__global__ __launch_bounds__(256) void prep_w_kernel(
    const float* __restrict__ weight, const float* __restrict__ root_w,
    unsigned short* __restrict__ wt, int* __restrict__ cursor, int nb)
{
    int g = blockIdx.x * 256 + threadIdx.x;
    if (g <= nb) cursor[g] = 0;
    if (g >= 5 * 4096) return;
    int m = g >> 12, rem = g & 4095, c = rem >> 6, k = rem & 63;
    float v = (m < 4) ? weight[m * 4096 + k * 64 + c] : root_w[k * 64 + c];
    int byte = m * 8192 + c * 128 + ((k * 2) ^ ((c & 7) << 4));
    wt[byte >> 1] = f2bf(v);
}

// ---------------------------------------------------------------------------
// Fused histA ∥ gemm.
//   blocks [0,nblk): per-chunk LDS histogram -> counts[blk*nb + b] (coalesced,
//   ZERO global atomics).
//   blocks [nblk, nblk+gemmBlocks): MFMA GEMM (operand-swapped).
// ---------------------------------------------------------------------------
__global__ __launch_bounds__(256) void fused_hg_kernel(
    const float* __restrict__ x, const uint4* __restrict__ wt4,
    const float* __restrict__ root_b,
    float* __restrict__ out, unsigned short* __restrict__ y, int n_nodes,
    const int* __restrict__ ei, int* __restrict__ counts,
    int n_edges, int nb, int nblk)
{
    __shared__ __align__(16) char smem[49152];
    const int tid = threadIdx.x;

    if (blockIdx.x < nblk) {
        int* lh = (int*)smem;            // nb <= NBMAX1
        for (int i = tid; i < nb; i += 256) lh[i] = 0;
        __syncthreads();
        const int chunk = (n_edges + nblk - 1) / nblk;
        const int lo = blockIdx.x * chunk;
        const int hi = min(lo + chunk, n_edges);
        for (int e = lo + tid; e < hi; e += 256)
            atomicAdd(&lh[ei[n_edges + e] >> 6], 1);
        __syncthreads();
        for (int i = tid; i < nb; i += 256)
            counts[(size_t)blockIdx.x * nb + i] = lh[i];
        return;
    }

    // --------------------------- GEMM path ---------------------------------
    uint4* lds4 = (uint4*)smem;          // 3072 entries
    const int node0 = (blockIdx.x - nblk) * 64;

    for (int i = tid; i < 2560; i += 256) lds4[512 + i] = wt4[i];

    {
        int n    = tid >> 2;
        int kq   = tid & 3;
        int node = node0 + n;
        uint4 p0, p1;
        if (node < n_nodes) {
            const float4* src = reinterpret_cast<const float4*>(x)
                                + (size_t)node * 16 + kq * 4;
            float4 f0 = src[0], f1 = src[1], f2 = src[2], f3 = src[3];
            p0.x = pack2(f0.x, f0.y); p0.y = pack2(f0.z, f0.w);
            p0.z = pack2(f1.x, f1.y); p0.w = pack2(f1.z, f1.w);
            p1.x = pack2(f2.x, f2.y); p1.y = pack2(f2.z, f2.w);
            p1.z = pack2(f3.x, f3.y); p1.w = pack2(f3.z, f3.w);
        } else {
            p0 = make_uint4(0, 0, 0, 0);
            p1 = p0;
        }
        int s0 = (kq * 2) ^ (n & 7);
        lds4[n * 8 + s0]       = p0;
        lds4[n * 8 + (s0 ^ 1)] = p1;
    }
    __syncthreads();

    const int wv = tid >> 6;
    const int l  = tid & 63;
    const int lo = l & 15;
    const int hi = l >> 4;

    const int arow = wv * 16 + lo;
    bf16x8 xb0 = *reinterpret_cast<const bf16x8*>(
        &lds4[arow * 8 + ((0 + hi) ^ (arow & 7))]);
    bf16x8 xb1 = *reinterpret_cast<const bf16x8*>(
        &lds4[arow * 8 + ((4 + hi) ^ (arow & 7))]);

    const int node   = node0 + wv * 16 + lo;
    const bool valid = (node < n_nodes);

    for (int m = 0; m < 5; ++m) {
        f32x4 acc[4];
        #pragma unroll
        for (int j = 0; j < 4; ++j)
            acc[j] = (f32x4){0.f, 0.f, 0.f, 0.f};

        #pragma unroll
        for (int j = 0; j < 4; ++j) {
            int c     = j * 16 + lo;
            int bbase = 512 + m * 512 + c * 8;
            bf16x8 w0 = *reinterpret_cast<const bf16x8*>(
                &lds4[bbase + ((0 + hi) ^ (c & 7))]);
            acc[j] = __builtin_amdgcn_mfma_f32_16x16x32_bf16(w0, xb0, acc[j], 0, 0, 0);
            bf16x8 w1 = *reinterpret_cast<const bf16x8*>(
                &lds4[bbase + ((4 + hi) ^ (c & 7))]);
            acc[j] = __builtin_amdgcn_mfma_f32_16x16x32_bf16(w1, xb1, acc[j], 0, 0, 0);
        }

        if (m < 4) {
            if (valid) {
                unsigned short* __restrict__ ym = y + (size_t)m * n_nodes * 64;
                #pragma unroll
                for (int j = 0; j < 4; ++j) {
                    uint2 o;
                    o.x = pack2(acc[j][0], acc[j][1]);
                    o.y = pack2(acc[j][2], acc[j][3]);
                    *reinterpret_cast<uint2*>(
                        &ym[(size_t)node * 64 + j * 16 + hi * 4]) = o;
                }
            }
        } else {
            if (valid) {
                #pragma unroll
                for (int j = 0; j < 4; ++j) {
                    float4 rb = reinterpret_cast<const float4*>(root_b)[j * 4 + hi];
                    float4 o  = make_float4(acc[j][0] + rb.x, acc[j][1] + rb.y,
                                            acc[j][2] + rb.z, acc[j][3] + rb.w);
                    *reinterpret_cast<float4*>(
                        &out[(size_t)node * 64 + j * 16 + hi * 4]) = o;
                }
            }
        }
    }
}

// ---------------------------------------------------------------------------
// scanB: thread-per-bucket prefix over fill blocks.
//   starts[i*nb+b] = sum_{j<i} counts[j*nb+b];  cursor[b] = bucket total.
// ---------------------------------------------------------------------------
__global__ __launch_bounds__(256) void scanb_kernel(
    const int* __restrict__ counts, int* __restrict__ starts,
    int* __restrict__ cursor, int nb, int nblk)
{
    int b = blockIdx.x * 256 + threadIdx.x;
    if (b >= nb) return;
    int run = 0;
    #pragma unroll 4
    for (int i = 0; i < nblk; ++i) {
        int c = counts[(size_t)i * nb + b];
        starts[(size_t)i * nb + b] = run;
        run += c;
    }
    cursor[b] = run;
}

// ---------------------------------------------------------------------------
// fillC: per-block LDS counting sort of its chunk, then contiguous run writes
// at deterministic positions (b*CAPB + starts[blk][b] + localrank).
// NO global atomics (spill only on overflow, never for this input).
// payload value = src | ldst<<ssh | type<<tsh
// ---------------------------------------------------------------------------
__global__ __launch_bounds__(256) void fillc_kernel(
    const int* __restrict__ ei, const int* __restrict__ et,
    const int* __restrict__ starts, int* __restrict__ cursor,
    int2* __restrict__ spill, unsigned* __restrict__ payload,
    int n_edges, int nb, int nblk, int ssh, int tsh)
{
    __shared__ unsigned pl[CHUNKMAX];
    __shared__ int lh[NBMAX1];
    __shared__ int loff[NBMAX1 + 1];
    __shared__ int tsum[256];

    const int tid   = threadIdx.x;
    const int blk   = blockIdx.x;
    const int chunk = (n_edges + nblk - 1) / nblk;
    const int lo    = blk * chunk;
    const int hi    = min(lo + chunk, n_edges);
    const int n     = hi - lo;

    for (int i = tid; i < nb; i += 256) lh[i] = 0;
    __syncthreads();
    for (int i = tid; i < n; i += 256)
        atomicAdd(&lh[ei[n_edges + lo + i] >> 6], 1);
    __syncthreads();

    // exclusive scan lh[0..nb) -> loff
    const int bins  = (nb + 255) / 256;
    const int base_ = tid * bins;
    int s = 0;
    for (int j = 0; j < bins; ++j) {
        int idx = base_ + j;
        if (idx < nb) s += lh[idx];
    }
    tsum[tid] = s;
    __syncthreads();
    for (int d = 1; d < 256; d <<= 1) {
        int v = (tid >= d) ? tsum[tid - d] : 0;
        __syncthreads();
        tsum[tid] += v;
        __syncthreads();
    }
    int run = (tid == 0) ? 0 : tsum[tid - 1];
    for (int j = 0; j < bins; ++j) {
        int idx = base_ + j;
        if (idx < nb) { loff[idx] = run; run += lh[idx]; }
    }
    if (tid == 255) loff[nb] = tsum[255];
    __syncthreads();
    for (int i = tid; i < nb; i += 256) lh[i] = 0;
    __syncthreads();

    // ranked placement into LDS (LDS atomics only)
    for (int i = tid; i < n; i += 256) {
        int e   = lo + i;
        int src = ei[e];
        int dn  = ei[n_edges + e];
        int t   = et[e];
        int b   = dn >> 6;
        int r   = atomicAdd(&lh[b], 1);
        pl[loff[b] + r] = (unsigned)src | ((unsigned)(dn & 63) << ssh)
                        | ((unsigned)t << tsh);
    }
    __syncthreads();

    // write out: consecutive i -> consecutive payload addrs within each run
    const int* __restrict__ srow = starts + (size_t)blk * nb;
    for (int i = tid; i < n; i += 256) {
        int lo2 = 0, hi2 = nb;
        while (hi2 - lo2 > 1) {              // binary search bucket of slot i
            int mid = (lo2 + hi2) >> 1;
            if (loff[mid] <= i) lo2 = mid; else hi2 = mid;
        }
        int b    = lo2;
        int rank = srow[b] + (i - loff[b]);
        unsigned v = pl[i];
        if (rank < CAPB) {
            payload[(size_t)b * CAPB + rank] = v;
        } else {
            int sp = atomicAdd(&cursor[nb], 1);
            spill[sp] = make_int2(b, (int)v);
        }
    }
}

// ---------------------------------------------------------------------------
// Gather: one 1024-thread block per bucket; in-LDS counting sort by local dst,
// 64 groups x 16 threads accumulate in registers (unroll x2). int2 spill.
// ---------------------------------------------------------------------------
__global__ __launch_bounds__(1024) void gatherb5_kernel(
    const int* __restrict__ cursor, const unsigned* __restrict__ payload,
    const int2* __restrict__ spill,
    const unsigned short* __restrict__ y, float* __restrict__ out,
    int n_nodes, int nb, int ssh, int tsh)
{
    __shared__ unsigned raw[CAPB];
    __shared__ unsigned srt[CAPB];
    __shared__ int hist[64];
    __shared__ int hoff[65];

    const int tid = threadIdx.x;
    const int b   = blockIdx.x;
    const int n_in = min(cursor[b], CAPB);
    const unsigned* __restrict__ pl_base = payload + (size_t)b * CAPB;

    if (tid < 64) hist[tid] = 0;
    __syncthreads();
    for (int i = tid; i < n_in; i += 1024) {
        unsigned pl = pl_base[i];
        raw[i] = pl;
        atomicAdd(&hist[(pl >> ssh) & 63], 1);
    }
    __syncthreads();
    if (tid < 64) {                       // wave-parallel exclusive scan
        int v = hist[tid];
        int s = v;
        #pragma unroll
        for (int d = 1; d < 64; d <<= 1) {
            int u = __shfl_up(s, d, 64);
            if (tid >= d) s += u;
        }
        hoff[tid] = s - v;
        if (tid == 63) hoff[64] = s;
        hist[tid] = 0;
    }
    __syncthreads();
    for (int i = tid; i < n_in; i += 1024) {
        unsigned pl = raw[i];
        int lnode = (pl >> ssh) & 63;
        int r = atomicAdd(&hist[lnode], 1);
        srt[hoff[lnode] + r] = pl;
    }
    __syncthreads();

    const int g    = tid >> 4;
    const int cq   = tid & 15;
    const int node = b * 64 + g;
    const unsigned smask = (1u << ssh) - 1;
    const ushort4* __restrict__ y4 = reinterpret_cast<const ushort4*>(y);

    float4 acc = make_float4(0.f, 0.f, 0.f, 0.f);
    const int s0 = hoff[g];
    const int s1 = hoff[g + 1];
    int p = s0;
    for (; p + 1 < s1; p += 2) {
        unsigned pl0 = srt[p];
        unsigned pl1 = srt[p + 1];
        ushort4 v0 = y4[((long)(pl0 >> tsh) * n_nodes + (pl0 & smask)) * 16 + cq];
        ushort4 v1 = y4[((long)(pl1 >> tsh) * n_nodes + (pl1 & smask)) * 16 + cq];
        acc.x += bf2f(v0.x) + bf2f(v1.x);
        acc.y += bf2f(v0.y) + bf2f(v1.y);
        acc.z += bf2f(v0.z) + bf2f(v1.z);
        acc.w += bf2f(v0.w) + bf2f(v1.w);
    }
    if (p < s1) {
        unsigned pl = srt[p];
        ushort4 v = y4[((long)(pl >> tsh) * n_nodes + (pl & smask)) * 16 + cq];
        acc.x += bf2f(v.x); acc.y += bf2f(v.y);
        acc.z += bf2f(v.z); acc.w += bf2f(v.w);
    }

    // Spill drain (normally S == 0).
    const int S = cursor[nb];
    for (int i = 0; i < S; ++i) {
        int2 sp = spill[i];
        if (sp.x == b) {
            unsigned v = (unsigned)sp.y;
            if ((int)((v >> ssh) & 63) == g) {
                int src = (int)(v & smask);
                int t   = (int)(v >> tsh);
                ushort4 w = y4[((long)t * n_nodes + src) * 16 + cq];
                acc.x += bf2f(w.x); acc.y += bf2f(w.y);
                acc.z += bf2f(w.z); acc.w += bf2f(w.w);
            }
        }
    }

    if (node < n_nodes) {
        float4* o  = reinterpret_cast<float4*>(out) + (long)node * 16 + cq;
        float4 cur = *o;
        cur.x += acc.x; cur.y += acc.y; cur.z += acc.z; cur.w += acc.w;
        *o = cur;
    }
}

// --------------------- fallbacks (small workspace) -------------------------
__global__ __launch_bounds__(256) void gemm_fused2_kernel(
    const float* __restrict__ x, const float* __restrict__ weight,
    const float* __restrict__ root_w, const float* __restrict__ root_b,
    float* __restrict__ out, unsigned short* __restrict__ y, int n_nodes)
{
    __shared__ unsigned short xsT[64][72];
    __shared__ float ws[64][72];
    const int tid   = threadIdx.x;
    const int node0 = blockIdx.x * 64;
    #pragma unroll
    for (int i = 0; i < 4; ++i) {
        int v    = tid + i * 256;
        int r    = v >> 4;
        int cq   = v & 15;
        int node = node0 + r;
        float4 x4 = (node < n_nodes)
                        ? reinterpret_cast<const float4*>(x)[(size_t)node * 16 + cq]
                        : make_float4(0.f, 0.f, 0.f, 0.f);
        xsT[cq * 4 + 0][r] = f2bf(x4.x);
        xsT[cq * 4 + 1][r] = f2bf(x4.y);
        xsT[cq * 4 + 2][r] = f2bf(x4.z);
        xsT[cq * 4 + 3][r] = f2bf(x4.w);
    }
    const int ng = tid & 31;
    const int cg = tid >> 5;
    float bias[8];
    #pragma unroll
    for (int j = 0; j < 8; ++j) bias[j] = root_b[cg * 8 + j];
    for (int m = 0; m < 5; ++m) {
        const float* __restrict__ W = (m < 4) ? (weight + m * 4096) : root_w;
        __syncthreads();
        #pragma unroll
        for (int i = 0; i < 4; ++i) {
            int v  = tid + i * 256;
            int r  = v >> 4;
            int cq = v & 15;
            float4 w4 = reinterpret_cast<const float4*>(W)[v];
            ws[r][cq * 4 + 0] = w4.x; ws[r][cq * 4 + 1] = w4.y;
            ws[r][cq * 4 + 2] = w4.z; ws[r][cq * 4 + 3] = w4.w;
        }
        __syncthreads();
        float acc[2][8];
        #pragma unroll
        for (int i = 0; i < 2; ++i)
            #pragma unroll
            for (int j = 0; j < 8; ++j) acc[i][j] = 0.f;
        #pragma unroll 4
        for (int k = 0; k < 64; ++k) {
            unsigned xu = *reinterpret_cast<const unsigned*>(&xsT[k][ng * 2]);
            float xv0 = __builtin_bit_cast(float, xu << 16);
            float xv1 = __builtin_bit_cast(float, xu & 0xffff0000u);
            float4 wa = *reinterpret_cast<const float4*>(&ws[k][cg * 8]);
            float4 wb = *reinterpret_cast<const float4*>(&ws[k][cg * 8 + 4]);
            float wv[8] = {wa.x, wa.y, wa.z, wa.w, wb.x, wb.y, wb.z, wb.w};
            #pragma unroll
            for (int j = 0; j < 8; ++j) {
                acc[0][j] += xv0 * wv[j];
                acc[1][j] += xv1 * wv[j];
            }
        }
        #pragma unroll
        for (int i = 0; i < 2; ++i) {
            int node = node0 + ng * 2 + i;
            if (node >= n_nodes) continue;
            if (m < 4) {
                uint4 o;
                o.x = pack2(acc[i][0], acc[i][1]);
                o.y = pack2(acc[i][2], acc[i][3]);
                o.z = pack2(acc[i][4], acc[i][5]);
                o.w = pack2(acc[i][6], acc[i][7]);
                *reinterpret_cast<uint4*>(
                    &y[((size_t)m * n_nodes + node) * 64 + cg * 8]) = o;
            } else {
                float4 oa = make_float4(acc[i][0] + bias[0], acc[i][1] + bias[1],
                                        acc[i][2] + bias[2], acc[i][3] + bias[3]);
                float4 ob = make_float4(acc[i][4] + bias[4], acc[i][5] + bias[5],
                                        acc[i][6] + bias[6], acc[i][7] + bias[7]);
                reinterpret_cast<float4*>(&out[(size_t)node * 64 + cg * 8])[0] = oa;
                reinterpret_cast<float4*>(&out[(size_t)node * 64 + cg * 8])[1] = ob;
            }
        }
    }
}

__global__ __launch_bounds__(256) void scatter_kernel(
    const int* __restrict__ ei, const int* __restrict__ et,
    const unsigned short* __restrict__ y, float* __restrict__ out,
    int n_edges, int n_nodes)
{
    long idx = (long)blockIdx.x * blockDim.x + threadIdx.x;
    if (idx >= (long)n_edges * 16) return;
    int e  = (int)(idx >> 4);
    int cq = (int)(idx & 15);
    int src  = ei[e];
    int dstn = ei[n_edges + e];
    int t    = et[e];
    ushort4 v = reinterpret_cast<const ushort4*>(y)[((long)t * n_nodes + src) * 16 + cq];
    float* o = out + (long)dstn * 64 + cq * 4;
    atomicAdd(o + 0, bf2f(v.x));
    atomicAdd(o + 1, bf2f(v.y));
    atomicAdd(o + 2, bf2f(v.z));
    atomicAdd(o + 3, bf2f(v.w));
}

__global__ __launch_bounds__(256) void gemm_root_kernel(
    const float* __restrict__ x, const float* __restrict__ root_w,
    const float* __restrict__ root_b, float* __restrict__ out, int n_nodes)
{
    __shared__ float xs[NT][65];
    __shared__ float ws[64][65];
    const int tid   = threadIdx.x;
    const int node0 = blockIdx.x * NT;
    #pragma unroll
    for (int i = 0; i < 4; ++i) {
        int v  = tid + i * 256;
        int r  = v >> 4;
        int cq = v & 15;
        float4 w4 = reinterpret_cast<const float4*>(root_w)[v];
        ws[r][cq * 4 + 0] = w4.x; ws[r][cq * 4 + 1] = w4.y;
        ws[r][cq * 4 + 2] = w4.z; ws[r][cq * 4 + 3] = w4.w;
        int node = node0 + r;
        float4 x4 = (node < n_nodes)
                        ? reinterpret_cast<const float4*>(x)[node * 16 + cq]
                        : make_float4(0.f, 0.f, 0.f, 0.f);
        xs[r][cq * 4 + 0] = x4.x; xs[r][cq * 4 + 1] = x4.y;
        xs[r][cq * 4 + 2] = x4.z; xs[r][cq * 4 + 3] = x4.w;
    }
    __syncthreads();
    const int tc = (tid & 15) * 4;
    const int tr = (tid >> 4) * 4;
    float acc[4][4];
    #pragma unroll
    for (int i = 0; i < 4; ++i)
        #pragma unroll
        for (int j = 0; j < 4; ++j) acc[i][j] = 0.f;
    #pragma unroll 4
    for (int k = 0; k < 64; ++k) {
        float xv[4], wv[4];
        #pragma unroll
        for (int i = 0; i < 4; ++i) xv[i] = xs[tr + i][k];
        #pragma unroll
        for (int j = 0; j < 4; ++j) wv[j] = ws[k][tc + j];
        #pragma unroll
        for (int i = 0; i < 4; ++i)
            #pragma unroll
            for (int j = 0; j < 4; ++j) acc[i][j] += xv[i] * wv[j];
    }
    #pragma unroll
    for (int i = 0; i < 4; ++i) {
        int node = node0 + tr + i;
        if (node < n_nodes) {
            float4 o = make_float4(acc[i][0] + root_b[tc + 0], acc[i][1] + root_b[tc + 1],
                                   acc[i][2] + root_b[tc + 2], acc[i][3] + root_b[tc + 3]);
            reinterpret_cast<float4*>(out)[node * 16 + (tc >> 2)] = o;
        }
    }
}

__global__ __launch_bounds__(256) void edge_direct_kernel(
    const float* __restrict__ x, const int* __restrict__ ei,
    const int* __restrict__ et, const float* __restrict__ weight,
    float* __restrict__ out, int n_edges)
{
    int gwave  = (int)((blockIdx.x * (long)blockDim.x + threadIdx.x) >> 6);
    int lane   = threadIdx.x & 63;
    int nwaves = (int)(((long)gridDim.x * blockDim.x) >> 6);
    for (int e = gwave; e < n_edges; e += nwaves) {
        int src  = ei[e];
        int dstn = ei[n_edges + e];
        int t    = et[e];
        float xv = x[src * 64 + lane];
        const float* __restrict__ W = weight + t * 4096;
        float acc = 0.f;
        #pragma unroll 8
        for (int k = 0; k < 64; ++k) {
            float xk = __shfl(xv, k);
            acc += xk * W[k * 64 + lane];
        }
        atomicAdd(&out[(long)dstn * 64 + lane], acc);
    }
}

extern "C" void kernel_launch(void* const* d_in, const int* in_sizes, int n_in,
                              void* d_out, int out_size, void* d_ws, size_t ws_size,
                              hipStream_t stream) {
    const float* x      = (const float*)d_in[0];
    const int*   ei     = (const int*)d_in[1];   // [2, E] int32
    const int*   et     = (const int*)d_in[2];   // [E]
    const float* weight = (const float*)d_in[3]; // [4, 64, 64]
    const float* root_w = (const float*)d_in[4]; // [64, 64]
    const float* root_b = (const float*)d_in[5]; // [64]
    float* out = (float*)d_out;

    const int n_nodes = in_sizes[0] / 64;
    const int n_edges = in_sizes[2];
    const int nb      = (n_nodes + 63) >> 6;
    const int nblk    = (n_edges + CHUNKMAX - 1) / CHUNKMAX;   // fill blocks

    int ssh = 1;
    while ((1 << ssh) < n_nodes) ++ssh;   // bits for src
    const int tsh = ssh + 6;              // 6 bits for local dst

    const size_t wt_bytes = 5 * 4096 * sizeof(unsigned short);   // 40 KB
    const size_t y_bytes  = (size_t)4 * n_nodes * 64 * sizeof(unsigned short);
    const size_t b_bytes  = wt_bytes + y_bytes +
        ((size_t)nb + 1 + 2 * (size_t)nblk * nb + (size_t)nb * CAPB
         + 2 * (size_t)n_edges) * 4;

    const int gemm_blocks = (n_nodes + 63) / 64;

    if (nb <= NBMAX1 && tsh + 2 <= 32 && ws_size >= b_bytes) {
        unsigned short* wt      = (unsigned short*)d_ws;
        unsigned short* y       = (unsigned short*)((char*)d_ws + wt_bytes);
        int*            cursor  = (int*)((char*)d_ws + wt_bytes + y_bytes); // nb+1
        int*            counts  = cursor + nb + 1;                // nblk*nb
        int*            starts  = counts + (size_t)nblk * nb;     // nblk*nb
        unsigned*       payload = (unsigned*)(starts + (size_t)nblk * nb);
        int2*           spill   = (int2*)(payload + (size_t)nb * CAPB);

        prep_w_kernel<<<96, 256, 0, stream>>>(weight, root_w, wt, cursor, nb);
        fused_hg_kernel<<<nblk + gemm_blocks, 256, 0, stream>>>(
            x, (const uint4*)wt, root_b, out, y, n_nodes,
            ei, counts, n_edges, nb, nblk);
        scanb_kernel<<<(nb + 255) / 256, 256, 0, stream>>>(
            counts, starts, cursor, nb, nblk);
        fillc_kernel<<<nblk, 256, 0, stream>>>(
            ei, et, starts, cursor, spill, payload, n_edges, nb, nblk, ssh, tsh);
        gatherb5_kernel<<<nb, 1024, 0, stream>>>(
            cursor, payload, spill, y, out, n_nodes, nb, ssh, tsh);
    } else if (ws_size >= y_bytes) {
        unsigned short* y = (unsigned short*)d_ws;
        gemm_fused2_kernel<<<(n_nodes + 63) / 64, 256, 0, stream>>>(
            x, weight, root_w, root_b, out, y, n_nodes);
        long total  = (long)n_edges * 16;
        int  blocks = (int)((total + 255) / 256);
        scatter_kernel<<<blocks, 256, 0, stream>>>(ei, et, y, out, n_edges, n_nodes);
    } else {
        gemm_root_kernel<<<(n_nodes + NT - 1) / NT, 256, 0, stream>>>(
            x, root_w, root_b, out, n_nodes);
        edge_direct_kernel<<<4096, 256, 0, stream>>>(x, ei, et, weight, out, n_edges);
    }
}

// Round 14
// 108.466 us; speedup vs baseline: 1.0977x; 1.0977x over previous
//
#include <hip/hip_runtime.h>

#define NT 64
#define NBMAX1 1024   // max buckets for the fast path (nodes <= 65536)
#define CAPB 2048     // payload slots per bucket (mean ~1279 here)
#define CHUNK 2048    // edges per fill block

typedef short bf16x8 __attribute__((ext_vector_type(8)));
typedef float f32x4  __attribute__((ext_vector_type(4)));

__device__ __forceinline__ unsigned short f2bf(float f) {
    unsigned u = __builtin_bit_cast(unsigned, f);
    unsigned r = (u + 0x7fffu + ((u >> 16) & 1u)) >> 16;   // round-nearest-even
    return (unsigned short)r;
}
__device__ __forceinline__ float bf2f(unsigned short h) {
    return __builtin_bit_cast(float, (unsigned)h << 16);
}
__device__ __forceinline__ unsigned pack2(float a, float b) {
    return (unsigned)f2bf(a) | ((unsigned)f2bf(b) << 16);
}

// ---------------------------------------------------------------------------
// Prep: W -> bf16 transposed [m][col][k], XOR-swizzled. Zero cursor[0..nb]
// (cursor[nb] = spill count; cursor[0..nb) rewritten by scanB).
// ---------------------------------------------------------------------------
__global__ __launch_bounds__(256) void prep_w_kernel(
    const float* __restrict__ weight, const float* __restrict__ root_w,
    unsigned short* __restrict__ wt, int* __restrict__ cursor, int nb)
{
    int g = blockIdx.x * 256 + threadIdx.x;
    if (g <= nb) cursor[g] = 0;
    if (g >= 5 * 4096) return;
    int m = g >> 12, rem = g & 4095, c = rem >> 6, k = rem & 63;
    float v = (m < 4) ? weight[m * 4096 + k * 64 + c] : root_w[k * 64 + c];
    int byte = m * 8192 + c * 128 + ((k * 2) ^ ((c & 7) << 4));
    wt[byte >> 1] = f2bf(v);
}

// ---------------------------------------------------------------------------
// hist: per-chunk LDS histogram -> counts[blk*nb + b]. Zero global atomics.
// ---------------------------------------------------------------------------
__global__ __launch_bounds__(256) void hist_kernel(
    const int* __restrict__ ei, int* __restrict__ counts,
    int n_edges, int nb, int nblk)
{
    __shared__ int lh[NBMAX1];
    const int tid = threadIdx.x;
    for (int i = tid; i < nb; i += 256) lh[i] = 0;
    __syncthreads();
    const int lo = blockIdx.x * CHUNK;
    const int hi = min(lo + CHUNK, n_edges);
    for (int e = lo + tid; e < hi; e += 256)
        atomicAdd(&lh[ei[n_edges + e] >> 6], 1);
    __syncthreads();
    for (int i = tid; i < nb; i += 256)
        counts[(size_t)blockIdx.x * nb + i] = lh[i];
}

// ---------------------------------------------------------------------------
// scanB: thread-per-bucket prefix over fill blocks.
// ---------------------------------------------------------------------------
__global__ __launch_bounds__(256) void scanb_kernel(
    const int* __restrict__ counts, int* __restrict__ starts,
    int* __restrict__ cursor, int nb, int nblk)
{
    int b = blockIdx.x * 256 + threadIdx.x;
    if (b >= nb) return;
    int run = 0;
    #pragma unroll 4
    for (int i = 0; i < nblk; ++i) {
        int c = counts[(size_t)i * nb + b];
        starts[(size_t)i * nb + b] = run;
        run += c;
    }
    cursor[b] = run;
}

// ---------------------------------------------------------------------------
// Fused fillC ∥ gemm.
//  blocks [0,nblk): counting-sort chunk in LDS (bkt[] recorded -> NO binary
//  search), write contiguous runs at deterministic positions. No global
//  atomics (spill only on CAPB overflow — never for this input).
//  blocks [nblk, nblk+nb): MFMA GEMM (operand-swapped, vector stores).
// payload = src | ldst<<ssh | type<<tsh
// ---------------------------------------------------------------------------
__global__ __launch_bounds__(256) void fused_fg_kernel(
    const float* __restrict__ x, const uint4* __restrict__ wt4,
    const float* __restrict__ root_b,
    float* __restrict__ out, unsigned short* __restrict__ y, int n_nodes,
    const int* __restrict__ ei, const int* __restrict__ et,
    const int* __restrict__ starts, int* __restrict__ cursor,
    int2* __restrict__ spill, unsigned* __restrict__ payload,
    int n_edges, int nb, int nblk, int ssh, int tsh)
{
    __shared__ __align__(16) char smem[49152];
    const int tid = threadIdx.x;

    if (blockIdx.x < nblk) {
        // ------------------------- FILL path -------------------------------
        unsigned*       pl   = (unsigned*)smem;                    // CHUNK
        unsigned short* bkt  = (unsigned short*)(pl + CHUNK);      // CHUNK
        int*            lh   = (int*)(bkt + CHUNK);                // NBMAX1
        int*            loff = lh + NBMAX1;                        // NBMAX1+1
        int*            tsum = loff + NBMAX1 + 1;                  // 256

        const int blk = blockIdx.x;
        const int lo  = blk * CHUNK;
        const int hi  = min(lo + CHUNK, n_edges);
        const int n   = hi - lo;

        for (int i = tid; i < nb; i += 256) lh[i] = 0;
        __syncthreads();
        for (int i = tid; i < n; i += 256)
            atomicAdd(&lh[ei[n_edges + lo + i] >> 6], 1);
        __syncthreads();

        // exclusive scan lh[0..nb) -> loff
        const int bins  = (nb + 255) / 256;
        const int base_ = tid * bins;
        int s = 0;
        for (int j = 0; j < bins; ++j) {
            int idx = base_ + j;
            if (idx < nb) s += lh[idx];
        }
        tsum[tid] = s;
        __syncthreads();
        for (int d = 1; d < 256; d <<= 1) {
            int v = (tid >= d) ? tsum[tid - d] : 0;
            __syncthreads();
            tsum[tid] += v;
            __syncthreads();
        }
        int run = (tid == 0) ? 0 : tsum[tid - 1];
        for (int j = 0; j < bins; ++j) {
            int idx = base_ + j;
            if (idx < nb) { loff[idx] = run; run += lh[idx]; }
        }
        __syncthreads();
        for (int i = tid; i < nb; i += 256) lh[i] = 0;
        __syncthreads();

        // ranked placement into LDS; record bucket per slot
        for (int i = tid; i < n; i += 256) {
            int e   = lo + i;
            int src = ei[e];
            int dn  = ei[n_edges + e];
            int t   = et[e];
            int b   = dn >> 6;
            int r   = atomicAdd(&lh[b], 1);
            int slot = loff[b] + r;
            pl[slot]  = (unsigned)src | ((unsigned)(dn & 63) << ssh)
                      | ((unsigned)t << tsh);
            bkt[slot] = (unsigned short)b;
        }
        __syncthreads();

        // write out: direct bucket lookup, consecutive slots -> consecutive
        // payload addresses within each run.
        const int* __restrict__ srow = starts + (size_t)blk * nb;
        for (int i = tid; i < n; i += 256) {
            int b    = bkt[i];
            int rank = srow[b] + (i - loff[b]);
            unsigned v = pl[i];
            if (rank < CAPB) {
                payload[(size_t)b * CAPB + rank] = v;
            } else {
                int sp = atomicAdd(&cursor[nb], 1);
                spill[sp] = make_int2(b, (int)v);
            }
        }
        return;
    }

    // --------------------------- GEMM path ---------------------------------
    uint4* lds4 = (uint4*)smem;          // 3072 entries
    const int node0 = (blockIdx.x - nblk) * 64;

    for (int i = tid; i < 2560; i += 256) lds4[512 + i] = wt4[i];

    {
        int n    = tid >> 2;
        int kq   = tid & 3;
        int node = node0 + n;
        uint4 p0, p1;
        if (node < n_nodes) {
            const float4* src = reinterpret_cast<const float4*>(x)
                                + (size_t)node * 16 + kq * 4;
            float4 f0 = src[0], f1 = src[1], f2 = src[2], f3 = src[3];
            p0.x = pack2(f0.x, f0.y); p0.y = pack2(f0.z, f0.w);
            p0.z = pack2(f1.x, f1.y); p0.w = pack2(f1.z, f1.w);
            p1.x = pack2(f2.x, f2.y); p1.y = pack2(f2.z, f2.w);
            p1.z = pack2(f3.x, f3.y); p1.w = pack2(f3.z, f3.w);
        } else {
            p0 = make_uint4(0, 0, 0, 0);
            p1 = p0;
        }
        int s0 = (kq * 2) ^ (n & 7);
        lds4[n * 8 + s0]       = p0;
        lds4[n * 8 + (s0 ^ 1)] = p1;
    }
    __syncthreads();

    const int wv = tid >> 6;
    const int l  = tid & 63;
    const int lo = l & 15;
    const int hi = l >> 4;

    const int arow = wv * 16 + lo;
    bf16x8 xb0 = *reinterpret_cast<const bf16x8*>(
        &lds4[arow * 8 + ((0 + hi) ^ (arow & 7))]);
    bf16x8 xb1 = *reinterpret_cast<const bf16x8*>(
        &lds4[arow * 8 + ((4 + hi) ^ (arow & 7))]);

    const int node   = node0 + wv * 16 + lo;
    const bool valid = (node < n_nodes);

    for (int m = 0; m < 5; ++m) {
        f32x4 acc[4];
        #pragma unroll
        for (int j = 0; j < 4; ++j)
            acc[j] = (f32x4){0.f, 0.f, 0.f, 0.f};

        #pragma unroll
        for (int j = 0; j < 4; ++j) {
            int c     = j * 16 + lo;
            int bbase = 512 + m * 512 + c * 8;
            bf16x8 w0 = *reinterpret_cast<const bf16x8*>(
                &lds4[bbase + ((0 + hi) ^ (c & 7))]);
            acc[j] = __builtin_amdgcn_mfma_f32_16x16x32_bf16(w0, xb0, acc[j], 0, 0, 0);
            bf16x8 w1 = *reinterpret_cast<const bf16x8*>(
                &lds4[bbase + ((4 + hi) ^ (c & 7))]);
            acc[j] = __builtin_amdgcn_mfma_f32_16x16x32_bf16(w1, xb1, acc[j], 0, 0, 0);
        }

        if (m < 4) {
            if (valid) {
                unsigned short* __restrict__ ym = y + (size_t)m * n_nodes * 64;
                #pragma unroll
                for (int j = 0; j < 4; ++j) {
                    uint2 o;
                    o.x = pack2(acc[j][0], acc[j][1]);
                    o.y = pack2(acc[j][2], acc[j][3]);
                    *reinterpret_cast<uint2*>(
                        &ym[(size_t)node * 64 + j * 16 + hi * 4]) = o;
                }
            }
        } else {
            if (valid) {
                #pragma unroll
                for (int j = 0; j < 4; ++j) {
                    float4 rb = reinterpret_cast<const float4*>(root_b)[j * 4 + hi];
                    float4 o  = make_float4(acc[j][0] + rb.x, acc[j][1] + rb.y,
                                            acc[j][2] + rb.z, acc[j][3] + rb.w);
                    *reinterpret_cast<float4*>(
                        &out[(size_t)node * 64 + j * 16 + hi * 4]) = o;
                }
            }
        }
    }
}

// ---------------------------------------------------------------------------
// Gather: one 1024-thread block per bucket; in-LDS counting sort by local dst,
// 64 groups x 16 threads accumulate in registers (unroll x2). int2 spill.
// ---------------------------------------------------------------------------
__global__ __launch_bounds__(1024) void gatherb5_kernel(
    const int* __restrict__ cursor, const unsigned* __restrict__ payload,
    const int2* __restrict__ spill,
    const unsigned short* __restrict__ y, float* __restrict__ out,
    int n_nodes, int nb, int ssh, int tsh)
{
    __shared__ unsigned raw[CAPB];
    __shared__ unsigned srt[CAPB];
    __shared__ int hist[64];
    __shared__ int hoff[65];

    const int tid = threadIdx.x;
    const int b   = blockIdx.x;
    const int n_in = min(cursor[b], CAPB);
    const unsigned* __restrict__ pl_base = payload + (size_t)b * CAPB;

    if (tid < 64) hist[tid] = 0;
    __syncthreads();
    for (int i = tid; i < n_in; i += 1024) {
        unsigned pl = pl_base[i];
        raw[i] = pl;
        atomicAdd(&hist[(pl >> ssh) & 63], 1);
    }
    __syncthreads();
    if (tid < 64) {                       // wave-parallel exclusive scan
        int v = hist[tid];
        int s = v;
        #pragma unroll
        for (int d = 1; d < 64; d <<= 1) {
            int u = __shfl_up(s, d, 64);
            if (tid >= d) s += u;
        }
        hoff[tid] = s - v;
        if (tid == 63) hoff[64] = s;
        hist[tid] = 0;
    }
    __syncthreads();
    for (int i = tid; i < n_in; i += 1024) {
        unsigned pl = raw[i];
        int lnode = (pl >> ssh) & 63;
        int r = atomicAdd(&hist[lnode], 1);
        srt[hoff[lnode] + r] = pl;
    }
    __syncthreads();

    const int g    = tid >> 4;
    const int cq   = tid & 15;
    const int node = b * 64 + g;
    const unsigned smask = (1u << ssh) - 1;
    const ushort4* __restrict__ y4 = reinterpret_cast<const ushort4*>(y);

    float4 acc = make_float4(0.f, 0.f, 0.f, 0.f);
    const int s0 = hoff[g];
    const int s1 = hoff[g + 1];
    int p = s0;
    for (; p + 1 < s1; p += 2) {
        unsigned pl0 = srt[p];
        unsigned pl1 = srt[p + 1];
        ushort4 v0 = y4[((long)(pl0 >> tsh) * n_nodes + (pl0 & smask)) * 16 + cq];
        ushort4 v1 = y4[((long)(pl1 >> tsh) * n_nodes + (pl1 & smask)) * 16 + cq];
        acc.x += bf2f(v0.x) + bf2f(v1.x);
        acc.y += bf2f(v0.y) + bf2f(v1.y);
        acc.z += bf2f(v0.z) + bf2f(v1.z);
        acc.w += bf2f(v0.w) + bf2f(v1.w);
    }
    if (p < s1) {
        unsigned pl = srt[p];
        ushort4 v = y4[((long)(pl >> tsh) * n_nodes + (pl & smask)) * 16 + cq];
        acc.x += bf2f(v.x); acc.y += bf2f(v.y);
        acc.z += bf2f(v.z); acc.w += bf2f(v.w);
    }

    // Spill drain (normally S == 0).
    const int S = cursor[nb];
    for (int i = 0; i < S; ++i) {
        int2 sp = spill[i];
        if (sp.x == b) {
            unsigned v = (unsigned)sp.y;
            if ((int)((v >> ssh) & 63) == g) {
                int src = (int)(v & smask);
                int t   = (int)(v >> tsh);
                ushort4 w = y4[((long)t * n_nodes + src) * 16 + cq];
                acc.x += bf2f(w.x); acc.y += bf2f(w.y);
                acc.z += bf2f(w.z); acc.w += bf2f(w.w);
            }
        }
    }

    if (node < n_nodes) {
        float4* o  = reinterpret_cast<float4*>(out) + (long)node * 16 + cq;
        float4 cur = *o;
        cur.x += acc.x; cur.y += acc.y; cur.z += acc.z; cur.w += acc.w;
        *o = cur;
    }
}

// --------------------- fallbacks (small workspace) -------------------------
__global__ __launch_bounds__(256) void gemm_fused2_kernel(
    const float* __restrict__ x, const float* __restrict__ weight,
    const float* __restrict__ root_w, const float* __restrict__ root_b,
    float* __restrict__ out, unsigned short* __restrict__ y, int n_nodes)
{
    __shared__ unsigned short xsT[64][72];
    __shared__ float ws[64][72];
    const int tid   = threadIdx.x;
    const int node0 = blockIdx.x * 64;
    #pragma unroll
    for (int i = 0; i < 4; ++i) {
        int v    = tid + i * 256;
        int r    = v >> 4;
        int cq   = v & 15;
        int node = node0 + r;
        float4 x4 = (node < n_nodes)
                        ? reinterpret_cast<const float4*>(x)[(size_t)node * 16 + cq]
                        : make_float4(0.f, 0.f, 0.f, 0.f);
        xsT[cq * 4 + 0][r] = f2bf(x4.x);
        xsT[cq * 4 + 1][r] = f2bf(x4.y);
        xsT[cq * 4 + 2][r] = f2bf(x4.z);
        xsT[cq * 4 + 3][r] = f2bf(x4.w);
    }
    const int ng = tid & 31;
    const int cg = tid >> 5;
    float bias[8];
    #pragma unroll
    for (int j = 0; j < 8; ++j) bias[j] = root_b[cg * 8 + j];
    for (int m = 0; m < 5; ++m) {
        const float* __restrict__ W = (m < 4) ? (weight + m * 4096) : root_w;
        __syncthreads();
        #pragma unroll
        for (int i = 0; i < 4; ++i) {
            int v  = tid + i * 256;
            int r  = v >> 4;
            int cq = v & 15;
            float4 w4 = reinterpret_cast<const float4*>(W)[v];
            ws[r][cq * 4 + 0] = w4.x; ws[r][cq * 4 + 1] = w4.y;
            ws[r][cq * 4 + 2] = w4.z; ws[r][cq * 4 + 3] = w4.w;
        }
        __syncthreads();
        float acc[2][8];
        #pragma unroll
        for (int i = 0; i < 2; ++i)
            #pragma unroll
            for (int j = 0; j < 8; ++j) acc[i][j] = 0.f;
        #pragma unroll 4
        for (int k = 0; k < 64; ++k) {
            unsigned xu = *reinterpret_cast<const unsigned*>(&xsT[k][ng * 2]);
            float xv0 = __builtin_bit_cast(float, xu << 16);
            float xv1 = __builtin_bit_cast(float, xu & 0xffff0000u);
            float4 wa = *reinterpret_cast<const float4*>(&ws[k][cg * 8]);
            float4 wb = *reinterpret_cast<const float4*>(&ws[k][cg * 8 + 4]);
            float wv[8] = {wa.x, wa.y, wa.z, wa.w, wb.x, wb.y, wb.z, wb.w};
            #pragma unroll
            for (int j = 0; j < 8; ++j) {
                acc[0][j] += xv0 * wv[j];
                acc[1][j] += xv1 * wv[j];
            }
        }
        #pragma unroll
        for (int i = 0; i < 2; ++i) {
            int node = node0 + ng * 2 + i;
            if (node >= n_nodes) continue;
            if (m < 4) {
                uint4 o;
                o.x = pack2(acc[i][0], acc[i][1]);
                o.y = pack2(acc[i][2], acc[i][3]);
                o.z = pack2(acc[i][4], acc[i][5]);
                o.w = pack2(acc[i][6], acc[i][7]);
                *reinterpret_cast<uint4*>(
                    &y[((size_t)m * n_nodes + node) * 64 + cg * 8]) = o;
            } else {
                float4 oa = make_float4(acc[i][0] + bias[0], acc[i][1] + bias[1],
                                        acc[i][2] + bias[2], acc[i][3] + bias[3]);
                float4 ob = make_float4(acc[i][4] + bias[4], acc[i][5] + bias[5],
                                        acc[i][6] + bias[6], acc[i][7] + bias[7]);
                reinterpret_cast<float4*>(&out[(size_t)node * 64 + cg * 8])[0] = oa;
                reinterpret_cast<float4*>(&out[(size_t)node * 64 + cg * 8])[1] = ob;
            }
        }
    }
}

__global__ __launch_bounds__(256) void scatter_kernel(
    const int* __restrict__ ei, const int* __restrict__ et,
    const unsigned short* __restrict__ y, float* __restrict__ out,
    int n_edges, int n_nodes)
{
    long idx = (long)blockIdx.x * blockDim.x + threadIdx.x;
    if (idx >= (long)n_edges * 16) return;
    int e  = (int)(idx >> 4);
    int cq = (int)(idx & 15);
    int src  = ei[e];
    int dstn = ei[n_edges + e];
    int t    = et[e];
    ushort4 v = reinterpret_cast<const ushort4*>(y)[((long)t * n_nodes + src) * 16 + cq];
    float* o = out + (long)dstn * 64 + cq * 4;
    atomicAdd(o + 0, bf2f(v.x));
    atomicAdd(o + 1, bf2f(v.y));
    atomicAdd(o + 2, bf2f(v.z));
    atomicAdd(o + 3, bf2f(v.w));
}

__global__ __launch_bounds__(256) void gemm_root_kernel(
    const float* __restrict__ x, const float* __restrict__ root_w,
    const float* __restrict__ root_b, float* __restrict__ out, int n_nodes)
{
    __shared__ float xs[NT][65];
    __shared__ float ws[64][65];
    const int tid   = threadIdx.x;
    const int node0 = blockIdx.x * NT;
    #pragma unroll
    for (int i = 0; i < 4; ++i) {
        int v  = tid + i * 256;
        int r  = v >> 4;
        int cq = v & 15;
        float4 w4 = reinterpret_cast<const float4*>(root_w)[v];
        ws[r][cq * 4 + 0] = w4.x; ws[r][cq * 4 + 1] = w4.y;
        ws[r][cq * 4 + 2] = w4.z; ws[r][cq * 4 + 3] = w4.w;
        int node = node0 + r;
        float4 x4 = (node < n_nodes)
                        ? reinterpret_cast<const float4*>(x)[node * 16 + cq]
                        : make_float4(0.f, 0.f, 0.f, 0.f);
        xs[r][cq * 4 + 0] = x4.x; xs[r][cq * 4 + 1] = x4.y;
        xs[r][cq * 4 + 2] = x4.z; xs[r][cq * 4 + 3] = x4.w;
    }
    __syncthreads();
    const int tc = (tid & 15) * 4;
    const int tr = (tid >> 4) * 4;
    float acc[4][4];
    #pragma unroll
    for (int i = 0; i < 4; ++i)
        #pragma unroll
        for (int j = 0; j < 4; ++j) acc[i][j] = 0.f;
    #pragma unroll 4
    for (int k = 0; k < 64; ++k) {
        float xv[4], wv[4];
        #pragma unroll
        for (int i = 0; i < 4; ++i) xv[i] = xs[tr + i][k];
        #pragma unroll
        for (int j = 0; j < 4; ++j) wv[j] = ws[k][tc + j];
        #pragma unroll
        for (int i = 0; i < 4; ++i)
            #pragma unroll
            for (int j = 0; j < 4; ++j) acc[i][j] += xv[i] * wv[j];
    }
    #pragma unroll
    for (int i = 0; i < 4; ++i) {
        int node = node0 + tr + i;
        if (node < n_nodes) {
            float4 o = make_float4(acc[i][0] + root_b[tc + 0], acc[i][1] + root_b[tc + 1],
                                   acc[i][2] + root_b[tc + 2], acc[i][3] + root_b[tc + 3]);
            reinterpret_cast<float4*>(out)[node * 16 + (tc >> 2)] = o;
        }
    }
}

__global__ __launch_bounds__(256) void edge_direct_kernel(
    const float* __restrict__ x, const int* __restrict__ ei,
    const int* __restrict__ et, const float* __restrict__ weight,
    float* __restrict__ out, int n_edges)
{
    int gwave  = (int)((blockIdx.x * (long)blockDim.x + threadIdx.x) >> 6);
    int lane   = threadIdx.x & 63;
    int nwaves = (int)(((long)gridDim.x * blockDim.x) >> 6);
    for (int e = gwave; e < n_edges; e += nwaves) {
        int src  = ei[e];
        int dstn = ei[n_edges + e];
        int t    = et[e];
        float xv = x[src * 64 + lane];
        const float* __restrict__ W = weight + t * 4096;
        float acc = 0.f;
        #pragma unroll 8
        for (int k = 0; k < 64; ++k) {
            float xk = __shfl(xv, k);
            acc += xk * W[k * 64 + lane];
        }
        atomicAdd(&out[(long)dstn * 64 + lane], acc);
    }
}

extern "C" void kernel_launch(void* const* d_in, const int* in_sizes, int n_in,
                              void* d_out, int out_size, void* d_ws, size_t ws_size,
                              hipStream_t stream) {
    const float* x      = (const float*)d_in[0];
    const int*   ei     = (const int*)d_in[1];   // [2, E] int32
    const int*   et     = (const int*)d_in[2];   // [E]
    const float* weight = (const float*)d_in[3]; // [4, 64, 64]
    const float* root_w = (const float*)d_in[4]; // [64, 64]
    const float* root_b = (const float*)d_in[5]; // [64]
    float* out = (float*)d_out;

    const int n_nodes = in_sizes[0] / 64;
    const int n_edges = in_sizes[2];
    const int nb      = (n_nodes + 63) >> 6;
    const int nblk    = (n_edges + CHUNK - 1) / CHUNK;   // fill blocks

    int ssh = 1;
    while ((1 << ssh) < n_nodes) ++ssh;   // bits for src
    const int tsh = ssh + 6;              // 6 bits for local dst

    const size_t wt_bytes = 5 * 4096 * sizeof(unsigned short);   // 40 KB
    const size_t y_bytes  = (size_t)4 * n_nodes * 64 * sizeof(unsigned short);
    const size_t b_bytes  = wt_bytes + y_bytes +
        ((size_t)nb + 1 + 2 * (size_t)nblk * nb + (size_t)nb * CAPB
         + 2 * (size_t)n_edges) * 4;

    const int gemm_blocks = (n_nodes + 63) / 64;

    if (nb <= NBMAX1 && tsh + 2 <= 32 && ws_size >= b_bytes) {
        unsigned short* wt      = (unsigned short*)d_ws;
        unsigned short* y       = (unsigned short*)((char*)d_ws + wt_bytes);
        int*            cursor  = (int*)((char*)d_ws + wt_bytes + y_bytes); // nb+1
        int*            counts  = cursor + nb + 1;                // nblk*nb
        int*            starts  = counts + (size_t)nblk * nb;     // nblk*nb
        unsigned*       payload = (unsigned*)(starts + (size_t)nblk * nb);
        int2*           spill   = (int2*)(payload + (size_t)nb * CAPB);

        prep_w_kernel<<<96, 256, 0, stream>>>(weight, root_w, wt, cursor, nb);
        hist_kernel<<<nblk, 256, 0, stream>>>(ei, counts, n_edges, nb, nblk);
        scanb_kernel<<<(nb + 255) / 256, 256, 0, stream>>>(
            counts, starts, cursor, nb, nblk);
        fused_fg_kernel<<<nblk + gemm_blocks, 256, 0, stream>>>(
            x, (const uint4*)wt, root_b, out, y, n_nodes,
            ei, et, starts, cursor, spill, payload,
            n_edges, nb, nblk, ssh, tsh);
        gatherb5_kernel<<<nb, 1024, 0, stream>>>(
            cursor, payload, spill, y, out, n_nodes, nb, ssh, tsh);
    } else if (ws_size >= y_bytes) {
        unsigned short* y = (unsigned short*)d_ws;
        gemm_fused2_kernel<<<(n_nodes + 63) / 64, 256, 0, stream>>>(
            x, weight, root_w, root_b, out, y, n_nodes);
        long total  = (long)n_edges * 16;
        int  blocks = (int)((total + 255) / 256);
        scatter_kernel<<<blocks, 256, 0, stream>>>(ei, et, y, out, n_edges, n_nodes);
    } else {
        gemm_root_kernel<<<(n_nodes + NT - 1) / NT, 256, 0, stream>>>(
            x, root_w, root_b, out, n_nodes);
        edge_direct_kernel<<<4096, 256, 0, stream>>>(x, ei, et, weight, out, n_edges);
    }
}

// Round 15
// 65.137 us; speedup vs baseline: 1.8278x; 1.6652x over previous
//
#include <hip/hip_runtime.h>

#define NT 64
#define NBMAX1 1024   // max buckets for the fast path (nodes <= 65536)
#define CAPB 2048     // payload slots per bucket (mean ~1279 here)
#define CHUNK 4096    // edges per fill block
#define FTHR 512      // threads for ph / fused kernels

typedef short bf16x8 __attribute__((ext_vector_type(8)));
typedef float f32x4  __attribute__((ext_vector_type(4)));

__device__ __forceinline__ unsigned short f2bf(float f) {
    unsigned u = __builtin_bit_cast(unsigned, f);
    unsigned r = (u + 0x7fffu + ((u >> 16) & 1u)) >> 16;   // round-nearest-even
    return (unsigned short)r;
}
__device__ __forceinline__ float bf2f(unsigned short h) {
    return __builtin_bit_cast(float, (unsigned)h << 16);
}
__device__ __forceinline__ unsigned pack2(float a, float b) {
    return (unsigned)f2bf(a) | ((unsigned)f2bf(b) << 16);
}

// ---------------------------------------------------------------------------
// ph: prep W (bf16, transposed [m][col][k], XOR-swizzled) by all blocks'
// first 20480 threads, AND per-chunk LDS histogram -> counts[blk*nb+b]
// (blocks < nblk). Zero global atomics.
// ---------------------------------------------------------------------------
__global__ __launch_bounds__(FTHR) void ph_kernel(
    const float* __restrict__ weight, const float* __restrict__ root_w,
    unsigned short* __restrict__ wt,
    const int* __restrict__ ei, int* __restrict__ counts,
    int n_edges, int nb, int nblk)
{
    const int tid = threadIdx.x;
    int g = blockIdx.x * FTHR + tid;
    if (g < 5 * 4096) {
        int m = g >> 12, rem = g & 4095, c = rem >> 6, k = rem & 63;
        float v = (m < 4) ? weight[m * 4096 + k * 64 + c] : root_w[k * 64 + c];
        int byte = m * 8192 + c * 128 + ((k * 2) ^ ((c & 7) << 4));
        wt[byte >> 1] = f2bf(v);
    }
    if (blockIdx.x >= nblk) return;

    __shared__ int lh[NBMAX1];
    for (int i = tid; i < nb; i += FTHR) lh[i] = 0;
    __syncthreads();
    const int lo = blockIdx.x * CHUNK;
    const int hi = min(lo + CHUNK, n_edges);
    for (int e = lo + tid; e < hi; e += FTHR)
        atomicAdd(&lh[ei[n_edges + e] >> 6], 1);
    __syncthreads();
    for (int i = tid; i < nb; i += FTHR)
        counts[(size_t)blockIdx.x * nb + i] = lh[i];
}

// ---------------------------------------------------------------------------
// scanw: ONE WAVE PER BUCKET. shfl-scan across nblk chunks (rounds of 64).
// Writes starts[blk*nb+b] (exclusive prefix) and cursor[b] (total).
// cursor[nb] (spill count) zeroed here.
// ---------------------------------------------------------------------------
__global__ __launch_bounds__(256) void scanw_kernel(
    const int* __restrict__ counts, int* __restrict__ starts,
    int* __restrict__ cursor, int nb, int nblk)
{
    if (blockIdx.x == 0 && threadIdx.x == 0) cursor[nb] = 0;
    const int w    = (blockIdx.x * 256 + threadIdx.x) >> 6;
    const int lane = threadIdx.x & 63;
    if (w >= nb) return;
    const int b = w;
    int base = 0;
    for (int r = 0; r * 64 < nblk; ++r) {
        int i = r * 64 + lane;
        int c = (i < nblk) ? counts[(size_t)i * nb + b] : 0;
        int s = c;
        #pragma unroll
        for (int d = 1; d < 64; d <<= 1) {
            int u = __shfl_up(s, d, 64);
            if (lane >= d) s += u;
        }
        if (i < nblk) starts[(size_t)i * nb + b] = base + s - c;
        base += __shfl(s, 63, 64);
    }
    if (lane == 0) cursor[b] = base;
}

// ---------------------------------------------------------------------------
// Fused fillC ∥ gemm (FTHR=512 threads).
//  blocks [0,nblk): counting-sort chunk in LDS (bkt[] recorded), write
//  contiguous runs at deterministic positions. No global atomics.
//  blocks [nblk, ...): MFMA GEMM, 128-node tile, 8 waves.
// payload = src | ldst<<ssh | type<<tsh
// ---------------------------------------------------------------------------
__global__ __launch_bounds__(FTHR) void fused_fg_kernel(
    const float* __restrict__ x, const uint4* __restrict__ wt4,
    const float* __restrict__ root_b,
    float* __restrict__ out, unsigned short* __restrict__ y, int n_nodes,
    const int* __restrict__ ei, const int* __restrict__ et,
    const int* __restrict__ starts, int* __restrict__ cursor,
    int2* __restrict__ spill, unsigned* __restrict__ payload,
    int n_edges, int nb, int nblk, int ssh, int tsh)
{
    __shared__ __align__(16) char smem[57344];   // 56 KB
    const int tid = threadIdx.x;

    if (blockIdx.x < nblk) {
        // ------------------------- FILL path -------------------------------
        unsigned*       pl   = (unsigned*)smem;                    // CHUNK
        unsigned short* bkt  = (unsigned short*)(pl + CHUNK);      // CHUNK
        int*            lh   = (int*)(bkt + CHUNK);                // NBMAX1
        int*            loff = lh + NBMAX1;                        // NBMAX1+1
        int*            tsum = loff + NBMAX1 + 1;                  // FTHR

        const int blk = blockIdx.x;
        const int lo  = blk * CHUNK;
        const int hi  = min(lo + CHUNK, n_edges);
        const int n   = hi - lo;

        for (int i = tid; i < nb; i += FTHR) lh[i] = 0;
        __syncthreads();
        for (int i = tid; i < n; i += FTHR)
            atomicAdd(&lh[ei[n_edges + lo + i] >> 6], 1);
        __syncthreads();

        // exclusive scan lh[0..nb) -> loff
        const int bins  = (nb + FTHR - 1) / FTHR;
        const int base_ = tid * bins;
        int s = 0;
        for (int j = 0; j < bins; ++j) {
            int idx = base_ + j;
            if (idx < nb) s += lh[idx];
        }
        tsum[tid] = s;
        __syncthreads();
        for (int d = 1; d < FTHR; d <<= 1) {
            int v = (tid >= d) ? tsum[tid - d] : 0;
            __syncthreads();
            tsum[tid] += v;
            __syncthreads();
        }
        int run = (tid == 0) ? 0 : tsum[tid - 1];
        for (int j = 0; j < bins; ++j) {
            int idx = base_ + j;
            if (idx < nb) { loff[idx] = run; run += lh[idx]; }
        }
        __syncthreads();
        for (int i = tid; i < nb; i += FTHR) lh[i] = 0;
        __syncthreads();

        // ranked placement into LDS; record bucket per slot
        for (int i = tid; i < n; i += FTHR) {
            int e   = lo + i;
            int src = ei[e];
            int dn  = ei[n_edges + e];
            int t   = et[e];
            int b   = dn >> 6;
            int r   = atomicAdd(&lh[b], 1);
            int slot = loff[b] + r;
            pl[slot]  = (unsigned)src | ((unsigned)(dn & 63) << ssh)
                      | ((unsigned)t << tsh);
            bkt[slot] = (unsigned short)b;
        }
        __syncthreads();

        // write out: direct bucket lookup; consecutive slots -> consecutive
        // payload addresses within each run.
        const int* __restrict__ srow = starts + (size_t)blk * nb;
        for (int i = tid; i < n; i += FTHR) {
            int b    = bkt[i];
            int rank = srow[b] + (i - loff[b]);
            unsigned v = pl[i];
            if (rank < CAPB) {
                payload[(size_t)b * CAPB + rank] = v;
            } else {
                int sp = atomicAdd(&cursor[nb], 1);
                spill[sp] = make_int2(b, (int)v);
            }
        }
        return;
    }

    // --------------------------- GEMM path (128-node tile) -----------------
    uint4* lds4 = (uint4*)smem;          // x: [0,1024) ; Wt: [1024,3584)
    const int node0 = (blockIdx.x - nblk) * 128;

    for (int i = tid; i < 2560; i += FTHR) lds4[1024 + i] = wt4[i];

    {
        int n    = tid >> 2;             // 0..127
        int kq   = tid & 3;
        int node = node0 + n;
        uint4 p0, p1;
        if (node < n_nodes) {
            const float4* src = reinterpret_cast<const float4*>(x)
                                + (size_t)node * 16 + kq * 4;
            float4 f0 = src[0], f1 = src[1], f2 = src[2], f3 = src[3];
            p0.x = pack2(f0.x, f0.y); p0.y = pack2(f0.z, f0.w);
            p0.z = pack2(f1.x, f1.y); p0.w = pack2(f1.z, f1.w);
            p1.x = pack2(f2.x, f2.y); p1.y = pack2(f2.z, f2.w);
            p1.z = pack2(f3.x, f3.y); p1.w = pack2(f3.z, f3.w);
        } else {
            p0 = make_uint4(0, 0, 0, 0);
            p1 = p0;
        }
        int s0 = (kq * 2) ^ (n & 7);
        lds4[n * 8 + s0]       = p0;
        lds4[n * 8 + (s0 ^ 1)] = p1;
    }
    __syncthreads();

    const int wv = tid >> 6;             // 0..7
    const int l  = tid & 63;
    const int lo = l & 15;
    const int hi = l >> 4;

    const int arow = (wv >> 2) * 64 + (wv & 3) * 16 + lo;   // 0..127
    bf16x8 xb0 = *reinterpret_cast<const bf16x8*>(
        &lds4[arow * 8 + ((0 + hi) ^ (arow & 7))]);
    bf16x8 xb1 = *reinterpret_cast<const bf16x8*>(
        &lds4[arow * 8 + ((4 + hi) ^ (arow & 7))]);

    const int node   = node0 + arow;
    const bool valid = (node < n_nodes);

    for (int m = 0; m < 5; ++m) {
        f32x4 acc[4];
        #pragma unroll
        for (int j = 0; j < 4; ++j)
            acc[j] = (f32x4){0.f, 0.f, 0.f, 0.f};

        #pragma unroll
        for (int j = 0; j < 4; ++j) {
            int c     = j * 16 + lo;
            int bbase = 1024 + m * 512 + c * 8;
            bf16x8 w0 = *reinterpret_cast<const bf16x8*>(
                &lds4[bbase + ((0 + hi) ^ (c & 7))]);
            acc[j] = __builtin_amdgcn_mfma_f32_16x16x32_bf16(w0, xb0, acc[j], 0, 0, 0);
            bf16x8 w1 = *reinterpret_cast<const bf16x8*>(
                &lds4[bbase + ((4 + hi) ^ (c & 7))]);
            acc[j] = __builtin_amdgcn_mfma_f32_16x16x32_bf16(w1, xb1, acc[j], 0, 0, 0);
        }

        if (m < 4) {
            if (valid) {
                unsigned short* __restrict__ ym = y + (size_t)m * n_nodes * 64;
                #pragma unroll
                for (int j = 0; j < 4; ++j) {
                    uint2 o;
                    o.x = pack2(acc[j][0], acc[j][1]);
                    o.y = pack2(acc[j][2], acc[j][3]);
                    *reinterpret_cast<uint2*>(
                        &ym[(size_t)node * 64 + j * 16 + hi * 4]) = o;
                }
            }
        } else {
            if (valid) {
                #pragma unroll
                for (int j = 0; j < 4; ++j) {
                    float4 rb = reinterpret_cast<const float4*>(root_b)[j * 4 + hi];
                    float4 o  = make_float4(acc[j][0] + rb.x, acc[j][1] + rb.y,
                                            acc[j][2] + rb.z, acc[j][3] + rb.w);
                    *reinterpret_cast<float4*>(
                        &out[(size_t)node * 64 + j * 16 + hi * 4]) = o;
                }
            }
        }
    }
}

// ---------------------------------------------------------------------------
// Gather: one 1024-thread block per bucket; in-LDS counting sort by local dst,
// 64 groups x 16 threads accumulate in registers (unroll x2). int2 spill.
// ---------------------------------------------------------------------------
__global__ __launch_bounds__(1024) void gatherb5_kernel(
    const int* __restrict__ cursor, const unsigned* __restrict__ payload,
    const int2* __restrict__ spill,
    const unsigned short* __restrict__ y, float* __restrict__ out,
    int n_nodes, int nb, int ssh, int tsh)
{
    __shared__ unsigned raw[CAPB];
    __shared__ unsigned srt[CAPB];
    __shared__ int hist[64];
    __shared__ int hoff[65];

    const int tid = threadIdx.x;
    const int b   = blockIdx.x;
    const int n_in = min(cursor[b], CAPB);
    const unsigned* __restrict__ pl_base = payload + (size_t)b * CAPB;

    if (tid < 64) hist[tid] = 0;
    __syncthreads();
    for (int i = tid; i < n_in; i += 1024) {
        unsigned pl = pl_base[i];
        raw[i] = pl;
        atomicAdd(&hist[(pl >> ssh) & 63], 1);
    }
    __syncthreads();
    if (tid < 64) {                       // wave-parallel exclusive scan
        int v = hist[tid];
        int s = v;
        #pragma unroll
        for (int d = 1; d < 64; d <<= 1) {
            int u = __shfl_up(s, d, 64);
            if (tid >= d) s += u;
        }
        hoff[tid] = s - v;
        if (tid == 63) hoff[64] = s;
        hist[tid] = 0;
    }
    __syncthreads();
    for (int i = tid; i < n_in; i += 1024) {
        unsigned pl = raw[i];
        int lnode = (pl >> ssh) & 63;
        int r = atomicAdd(&hist[lnode], 1);
        srt[hoff[lnode] + r] = pl;
    }
    __syncthreads();

    const int g    = tid >> 4;
    const int cq   = tid & 15;
    const int node = b * 64 + g;
    const unsigned smask = (1u << ssh) - 1;
    const ushort4* __restrict__ y4 = reinterpret_cast<const ushort4*>(y);

    float4 acc = make_float4(0.f, 0.f, 0.f, 0.f);
    const int s0 = hoff[g];
    const int s1 = hoff[g + 1];
    int p = s0;
    for (; p + 1 < s1; p += 2) {
        unsigned pl0 = srt[p];
        unsigned pl1 = srt[p + 1];
        ushort4 v0 = y4[((long)(pl0 >> tsh) * n_nodes + (pl0 & smask)) * 16 + cq];
        ushort4 v1 = y4[((long)(pl1 >> tsh) * n_nodes + (pl1 & smask)) * 16 + cq];
        acc.x += bf2f(v0.x) + bf2f(v1.x);
        acc.y += bf2f(v0.y) + bf2f(v1.y);
        acc.z += bf2f(v0.z) + bf2f(v1.z);
        acc.w += bf2f(v0.w) + bf2f(v1.w);
    }
    if (p < s1) {
        unsigned pl = srt[p];
        ushort4 v = y4[((long)(pl >> tsh) * n_nodes + (pl & smask)) * 16 + cq];
        acc.x += bf2f(v.x); acc.y += bf2f(v.y);
        acc.z += bf2f(v.z); acc.w += bf2f(v.w);
    }

    // Spill drain (normally S == 0).
    const int S = cursor[nb];
    for (int i = 0; i < S; ++i) {
        int2 sp = spill[i];
        if (sp.x == b) {
            unsigned v = (unsigned)sp.y;
            if ((int)((v >> ssh) & 63) == g) {
                int src = (int)(v & smask);
                int t   = (int)(v >> tsh);
                ushort4 w = y4[((long)t * n_nodes + src) * 16 + cq];
                acc.x += bf2f(w.x); acc.y += bf2f(w.y);
                acc.z += bf2f(w.z); acc.w += bf2f(w.w);
            }
        }
    }

    if (node < n_nodes) {
        float4* o  = reinterpret_cast<float4*>(out) + (long)node * 16 + cq;
        float4 cur = *o;
        cur.x += acc.x; cur.y += acc.y; cur.z += acc.z; cur.w += acc.w;
        *o = cur;
    }
}

// --------------------- fallbacks (small workspace) -------------------------
__global__ __launch_bounds__(256) void gemm_fused2_kernel(
    const float* __restrict__ x, const float* __restrict__ weight,
    const float* __restrict__ root_w, const float* __restrict__ root_b,
    float* __restrict__ out, unsigned short* __restrict__ y, int n_nodes)
{
    __shared__ unsigned short xsT[64][72];
    __shared__ float ws[64][72];
    const int tid   = threadIdx.x;
    const int node0 = blockIdx.x * 64;
    #pragma unroll
    for (int i = 0; i < 4; ++i) {
        int v    = tid + i * 256;
        int r    = v >> 4;
        int cq   = v & 15;
        int node = node0 + r;
        float4 x4 = (node < n_nodes)
                        ? reinterpret_cast<const float4*>(x)[(size_t)node * 16 + cq]
                        : make_float4(0.f, 0.f, 0.f, 0.f);
        xsT[cq * 4 + 0][r] = f2bf(x4.x);
        xsT[cq * 4 + 1][r] = f2bf(x4.y);
        xsT[cq * 4 + 2][r] = f2bf(x4.z);
        xsT[cq * 4 + 3][r] = f2bf(x4.w);
    }
    const int ng = tid & 31;
    const int cg = tid >> 5;
    float bias[8];
    #pragma unroll
    for (int j = 0; j < 8; ++j) bias[j] = root_b[cg * 8 + j];
    for (int m = 0; m < 5; ++m) {
        const float* __restrict__ W = (m < 4) ? (weight + m * 4096) : root_w;
        __syncthreads();
        #pragma unroll
        for (int i = 0; i < 4; ++i) {
            int v  = tid + i * 256;
            int r  = v >> 4;
            int cq = v & 15;
            float4 w4 = reinterpret_cast<const float4*>(W)[v];
            ws[r][cq * 4 + 0] = w4.x; ws[r][cq * 4 + 1] = w4.y;
            ws[r][cq * 4 + 2] = w4.z; ws[r][cq * 4 + 3] = w4.w;
        }
        __syncthreads();
        float acc[2][8];
        #pragma unroll
        for (int i = 0; i < 2; ++i)
            #pragma unroll
            for (int j = 0; j < 8; ++j) acc[i][j] = 0.f;
        #pragma unroll 4
        for (int k = 0; k < 64; ++k) {
            unsigned xu = *reinterpret_cast<const unsigned*>(&xsT[k][ng * 2]);
            float xv0 = __builtin_bit_cast(float, xu << 16);
            float xv1 = __builtin_bit_cast(float, xu & 0xffff0000u);
            float4 wa = *reinterpret_cast<const float4*>(&ws[k][cg * 8]);
            float4 wb = *reinterpret_cast<const float4*>(&ws[k][cg * 8 + 4]);
            float wv[8] = {wa.x, wa.y, wa.z, wa.w, wb.x, wb.y, wb.z, wb.w};
            #pragma unroll
            for (int j = 0; j < 8; ++j) {
                acc[0][j] += xv0 * wv[j];
                acc[1][j] += xv1 * wv[j];
            }
        }
        #pragma unroll
        for (int i = 0; i < 2; ++i) {
            int node = node0 + ng * 2 + i;
            if (node >= n_nodes) continue;
            if (m < 4) {
                uint4 o;
                o.x = pack2(acc[i][0], acc[i][1]);
                o.y = pack2(acc[i][2], acc[i][3]);
                o.z = pack2(acc[i][4], acc[i][5]);
                o.w = pack2(acc[i][6], acc[i][7]);
                *reinterpret_cast<uint4*>(
                    &y[((size_t)m * n_nodes + node) * 64 + cg * 8]) = o;
            } else {
                float4 oa = make_float4(acc[i][0] + bias[0], acc[i][1] + bias[1],
                                        acc[i][2] + bias[2], acc[i][3] + bias[3]);
                float4 ob = make_float4(acc[i][4] + bias[4], acc[i][5] + bias[5],
                                        acc[i][6] + bias[6], acc[i][7] + bias[7]);
                reinterpret_cast<float4*>(&out[(size_t)node * 64 + cg * 8])[0] = oa;
                reinterpret_cast<float4*>(&out[(size_t)node * 64 + cg * 8])[1] = ob;
            }
        }
    }
}

__global__ __launch_bounds__(256) void scatter_kernel(
    const int* __restrict__ ei, const int* __restrict__ et,
    const unsigned short* __restrict__ y, float* __restrict__ out,
    int n_edges, int n_nodes)
{
    long idx = (long)blockIdx.x * blockDim.x + threadIdx.x;
    if (idx >= (long)n_edges * 16) return;
    int e  = (int)(idx >> 4);
    int cq = (int)(idx & 15);
    int src  = ei[e];
    int dstn = ei[n_edges + e];
    int t    = et[e];
    ushort4 v = reinterpret_cast<const ushort4*>(y)[((long)t * n_nodes + src) * 16 + cq];
    float* o = out + (long)dstn * 64 + cq * 4;
    atomicAdd(o + 0, bf2f(v.x));
    atomicAdd(o + 1, bf2f(v.y));
    atomicAdd(o + 2, bf2f(v.z));
    atomicAdd(o + 3, bf2f(v.w));
}

__global__ __launch_bounds__(256) void gemm_root_kernel(
    const float* __restrict__ x, const float* __restrict__ root_w,
    const float* __restrict__ root_b, float* __restrict__ out, int n_nodes)
{
    __shared__ float xs[NT][65];
    __shared__ float ws[64][65];
    const int tid   = threadIdx.x;
    const int node0 = blockIdx.x * NT;
    #pragma unroll
    for (int i = 0; i < 4; ++i) {
        int v  = tid + i * 256;
        int r  = v >> 4;
        int cq = v & 15;
        float4 w4 = reinterpret_cast<const float4*>(root_w)[v];
        ws[r][cq * 4 + 0] = w4.x; ws[r][cq * 4 + 1] = w4.y;
        ws[r][cq * 4 + 2] = w4.z; ws[r][cq * 4 + 3] = w4.w;
        int node = node0 + r;
        float4 x4 = (node < n_nodes)
                        ? reinterpret_cast<const float4*>(x)[node * 16 + cq]
                        : make_float4(0.f, 0.f, 0.f, 0.f);
        xs[r][cq * 4 + 0] = x4.x; xs[r][cq * 4 + 1] = x4.y;
        xs[r][cq * 4 + 2] = x4.z; xs[r][cq * 4 + 3] = x4.w;
    }
    __syncthreads();
    const int tc = (tid & 15) * 4;
    const int tr = (tid >> 4) * 4;
    float acc[4][4];
    #pragma unroll
    for (int i = 0; i < 4; ++i)
        #pragma unroll
        for (int j = 0; j < 4; ++j) acc[i][j] = 0.f;
    #pragma unroll 4
    for (int k = 0; k < 64; ++k) {
        float xv[4], wv[4];
        #pragma unroll
        for (int i = 0; i < 4; ++i) xv[i] = xs[tr + i][k];
        #pragma unroll
        for (int j = 0; j < 4; ++j) wv[j] = ws[k][tc + j];
        #pragma unroll
        for (int i = 0; i < 4; ++i)
            #pragma unroll
            for (int j = 0; j < 4; ++j) acc[i][j] += xv[i] * wv[j];
    }
    #pragma unroll
    for (int i = 0; i < 4; ++i) {
        int node = node0 + tr + i;
        if (node < n_nodes) {
            float4 o = make_float4(acc[i][0] + root_b[tc + 0], acc[i][1] + root_b[tc + 1],
                                   acc[i][2] + root_b[tc + 2], acc[i][3] + root_b[tc + 3]);
            reinterpret_cast<float4*>(out)[node * 16 + (tc >> 2)] = o;
        }
    }
}

__global__ __launch_bounds__(256) void edge_direct_kernel(
    const float* __restrict__ x, const int* __restrict__ ei,
    const int* __restrict__ et, const float* __restrict__ weight,
    float* __restrict__ out, int n_edges)
{
    int gwave  = (int)((blockIdx.x * (long)blockDim.x + threadIdx.x) >> 6);
    int lane   = threadIdx.x & 63;
    int nwaves = (int)(((long)gridDim.x * blockDim.x) >> 6);
    for (int e = gwave; e < n_edges; e += nwaves) {
        int src  = ei[e];
        int dstn = ei[n_edges + e];
        int t    = et[e];
        float xv = x[src * 64 + lane];
        const float* __restrict__ W = weight + t * 4096;
        float acc = 0.f;
        #pragma unroll 8
        for (int k = 0; k < 64; ++k) {
            float xk = __shfl(xv, k);
            acc += xk * W[k * 64 + lane];
        }
        atomicAdd(&out[(long)dstn * 64 + lane], acc);
    }
}

extern "C" void kernel_launch(void* const* d_in, const int* in_sizes, int n_in,
                              void* d_out, int out_size, void* d_ws, size_t ws_size,
                              hipStream_t stream) {
    const float* x      = (const float*)d_in[0];
    const int*   ei     = (const int*)d_in[1];   // [2, E] int32
    const int*   et     = (const int*)d_in[2];   // [E]
    const float* weight = (const float*)d_in[3]; // [4, 64, 64]
    const float* root_w = (const float*)d_in[4]; // [64, 64]
    const float* root_b = (const float*)d_in[5]; // [64]
    float* out = (float*)d_out;

    const int n_nodes = in_sizes[0] / 64;
    const int n_edges = in_sizes[2];
    const int nb      = (n_nodes + 63) >> 6;
    const int nblk    = (n_edges + CHUNK - 1) / CHUNK;   // fill blocks

    int ssh = 1;
    while ((1 << ssh) < n_nodes) ++ssh;   // bits for src
    const int tsh = ssh + 6;              // 6 bits for local dst

    const size_t wt_bytes = 5 * 4096 * sizeof(unsigned short);   // 40 KB
    const size_t y_bytes  = (size_t)4 * n_nodes * 64 * sizeof(unsigned short);
    const size_t b_bytes  = wt_bytes + y_bytes +
        ((size_t)nb + 1 + 2 * (size_t)nblk * nb + (size_t)nb * CAPB
         + 2 * (size_t)n_edges) * 4;

    const int gemm_blocks = (n_nodes + 127) / 128;

    if (nb <= NBMAX1 && tsh + 2 <= 32 && ws_size >= b_bytes) {
        unsigned short* wt      = (unsigned short*)d_ws;
        unsigned short* y       = (unsigned short*)((char*)d_ws + wt_bytes);
        int*            cursor  = (int*)((char*)d_ws + wt_bytes + y_bytes); // nb+1
        int*            counts  = cursor + nb + 1;                // nblk*nb
        int*            starts  = counts + (size_t)nblk * nb;     // nblk*nb
        unsigned*       payload = (unsigned*)(starts + (size_t)nblk * nb);
        int2*           spill   = (int2*)(payload + (size_t)nb * CAPB);

        const int ph_blocks = max(nblk, (5 * 4096 + FTHR - 1) / FTHR);
        ph_kernel<<<ph_blocks, FTHR, 0, stream>>>(
            weight, root_w, wt, ei, counts, n_edges, nb, nblk);
        scanw_kernel<<<(nb * 64 + 255) / 256, 256, 0, stream>>>(
            counts, starts, cursor, nb, nblk);
        fused_fg_kernel<<<nblk + gemm_blocks, FTHR, 0, stream>>>(
            x, (const uint4*)wt, root_b, out, y, n_nodes,
            ei, et, starts, cursor, spill, payload,
            n_edges, nb, nblk, ssh, tsh);
        gatherb5_kernel<<<nb, 1024, 0, stream>>>(
            cursor, payload, spill, y, out, n_nodes, nb, ssh, tsh);
    } else if (ws_size >= y_bytes) {
        unsigned short* y = (unsigned short*)d_ws;
        gemm_fused2_kernel<<<(n_nodes + 63) / 64, 256, 0, stream>>>(
            x, weight, root_w, root_b, out, y, n_nodes);
        long total  = (long)n_edges * 16;
        int  blocks = (int)((total + 255) / 256);
        scatter_kernel<<<blocks, 256, 0, stream>>>(ei, et, y, out, n_edges, n_nodes);
    } else {
        gemm_root_kernel<<<(n_nodes + NT - 1) / NT, 256, 0, stream>>>(
            x, root_w, root_b, out, n_nodes);
        edge_direct_kernel<<<4096, 256, 0, stream>>>(x, ei, et, weight, out, n_edges);
    }
}